// Round 1
// baseline (566.623 us; speedup 1.0000x reference)
//
#include <hip/hip_runtime.h>
#include <math.h>

// ---------------- problem constants ----------------
#define BD   8       // batch
#define TT   4096    // time
#define DD   1024    // feature dim
#define HH   8       // heads
#define KK   6       // picks
// d_out layout (floats): rep | indices | combined | dist | mu_q | sigma_q | loss
#define OFF_REP   0
#define OFF_IDX   49152
#define OFF_COMB  49200
#define OFF_DIST  81968
#define OFF_MU    114736
#define OFF_SG    122928
#define OFF_LOSS  131120
// ws layout (floats)
#define WS_X1     0        // 2*8*1024
#define WS_H      16384    // 2*8*1024
#define WS_Q      32768    // 8*1024
#define WS_P      40960    // 8*8*1024
#define WS_C      106496   // 64
#define WS_ISIG   106560   // 8*1024
#define WS_SCORES 114752   // 8*8*4096
#define WS_IDXI   376896   // 48 ints

#define INV_SQRT_DH 0.08838834764831845f  // 1/sqrt(128)

__device__ __forceinline__ float softplus_f(float x) {
  return fmaxf(x, 0.0f) + log1pf(expf(-fabsf(x)));
}

// ---- shared GEMV core: out[b,row] = in[b,:] . W[row,:]  (8 batches, wave per row)
__device__ __forceinline__ void gemv_rows_core(const float* __restrict__ in,
                                               const float* __restrict__ W,
                                               int row, float (*s_in)[DD], float acc[8]) {
  int tid = threadIdx.x;
  const float4* in4 = (const float4*)in;
  float4* s4 = (float4*)&s_in[0][0];
  for (int i = tid; i < 2048; i += 256) s4[i] = in4[i];
  __syncthreads();
  int lane = tid & 63;
  const float4* wr4 = (const float4*)(W + (size_t)row * DD);
#pragma unroll
  for (int b = 0; b < 8; ++b) acc[b] = 0.0f;
#pragma unroll
  for (int i = 0; i < 4; ++i) {
    int d4 = i * 64 + lane;
    float4 w4 = wr4[d4];
#pragma unroll
    for (int b = 0; b < 8; ++b) {
      float4 q4 = ((const float4*)&s_in[b][0])[d4];
      acc[b] += w4.x * q4.x + w4.y * q4.y + w4.z * q4.z + w4.w * q4.w;
    }
  }
#pragma unroll
  for (int off = 32; off; off >>= 1)
#pragma unroll
    for (int b = 0; b < 8; ++b) acc[b] += __shfl_xor(acc[b], off, 64);
}

// x1[path][b][row] = qe[b]·W{path}[row] + bias
__global__ __launch_bounds__(256) void k_gemv_pre(const float* __restrict__ qe,
    const float* __restrict__ W0, const float* __restrict__ W1,
    const float* __restrict__ b0, const float* __restrict__ b1, float* __restrict__ x1) {
  __shared__ float s_in[8][DD];
  int path = blockIdx.x >> 8;
  int row = (blockIdx.x & 255) * 4 + (threadIdx.x >> 6);
  const float* W = path ? W1 : W0;
  const float* bb = path ? b1 : b0;
  float acc[8];
  gemv_rows_core(qe, W, row, s_in, acc);
  if ((threadIdx.x & 63) == 0) {
    float bv = bb[row];
#pragma unroll
    for (int b = 0; b < 8; ++b) x1[path * 8192 + b * DD + row] = acc[b] + bv;
  }
}

// LN + relu per (path,b) row of 1024
__global__ __launch_bounds__(256) void k_ln(const float* __restrict__ x1,
    const float* __restrict__ g0, const float* __restrict__ be0,
    const float* __restrict__ g1, const float* __restrict__ be1, float* __restrict__ h) {
  int path = blockIdx.x >> 3, b = blockIdx.x & 7;
  const float* x = x1 + path * 8192 + b * DD;
  const float* g = path ? g1 : g0;
  const float* be = path ? be1 : be0;
  __shared__ float sx[DD];
  __shared__ float red[256];
  int tid = threadIdx.x;
  float ps = 0.0f;
  for (int i = tid; i < DD; i += 256) { float v = x[i]; sx[i] = v; ps += v; }
  red[tid] = ps; __syncthreads();
  for (int off = 128; off; off >>= 1) { if (tid < off) red[tid] += red[tid + off]; __syncthreads(); }
  float mean = red[0] * (1.0f / 1024.0f);
  __syncthreads();
  float pv = 0.0f;
  for (int i = tid; i < DD; i += 256) { float d = sx[i] - mean; pv += d * d; }
  red[tid] = pv; __syncthreads();
  for (int off = 128; off; off >>= 1) { if (tid < off) red[tid] += red[tid + off]; __syncthreads(); }
  float var = red[0] * (1.0f / 1024.0f);
  float inv = 1.0f / sqrtf(var + 1e-5f);
  for (int i = tid; i < DD; i += 256) {
    float v = (sx[i] - mean) * inv * g[i] + be[i];
    h[path * 8192 + b * DD + i] = v > 0.0f ? v : 0.0f;
  }
}

// path0: mu_q; path1: sigma_q = softplus+1e-6, isig = 1/sigma
__global__ __launch_bounds__(256) void k_gemv_mid(const float* __restrict__ h,
    const float* __restrict__ W0, const float* __restrict__ W1,
    const float* __restrict__ b0, const float* __restrict__ b1,
    float* __restrict__ mu_out, float* __restrict__ sg_out, float* __restrict__ isig) {
  __shared__ float s_in[8][DD];
  int path = blockIdx.x >> 8;
  int row = (blockIdx.x & 255) * 4 + (threadIdx.x >> 6);
  const float* W = path ? W1 : W0;
  const float* bb = path ? b1 : b0;
  float acc[8];
  gemv_rows_core(h + path * 8192, W, row, s_in, acc);
  if ((threadIdx.x & 63) == 0) {
    float bv = bb[row];
#pragma unroll
    for (int b = 0; b < 8; ++b) {
      float v = acc[b] + bv;
      if (path == 0) {
        mu_out[b * DD + row] = v;
      } else {
        float sp = softplus_f(v) + 1e-6f;
        sg_out[b * DD + row] = sp;
        isig[b * DD + row] = 1.0f / sp;
      }
    }
  }
}

// q[b,row] = mu_q[b]·wq[row] + bq[row]   (wq = in_w rows 0..1023)
__global__ __launch_bounds__(256) void k_gemv_q(const float* __restrict__ mu_q,
    const float* __restrict__ in_w, const float* __restrict__ in_b, float* __restrict__ q) {
  __shared__ float s_in[8][DD];
  int row = blockIdx.x * 4 + (threadIdx.x >> 6);
  float acc[8];
  gemv_rows_core(mu_q, in_w, row, s_in, acc);
  if ((threadIdx.x & 63) == 0) {
    float bv = in_b[row];
#pragma unroll
    for (int b = 0; b < 8; ++b) q[b * DD + row] = acc[b] + bv;
  }
}

// p[b,h,j] = (sum_r q[b,h*128+r]*wk[h*128+r,j]) / sqrt(128);  c[b,h] analog with bk
__global__ __launch_bounds__(256) void k_p(const float* __restrict__ q,
    const float* __restrict__ in_w, const float* __restrict__ in_b,
    float* __restrict__ p, float* __restrict__ c) {
  int hh = blockIdx.x >> 2;
  int j0 = (blockIdx.x & 3) * 256;
  __shared__ float qh[8][128];
  for (int i = threadIdx.x; i < 1024; i += 256) {
    int b = i >> 7, r = i & 127;
    qh[b][r] = q[b * DD + hh * 128 + r];
  }
  __syncthreads();
  const float* wbase = in_w + (size_t)(DD + hh * 128) * DD + j0 + threadIdx.x;
  float acc[8];
#pragma unroll
  for (int b = 0; b < 8; ++b) acc[b] = 0.0f;
  for (int r = 0; r < 128; ++r) {
    float w = wbase[(size_t)r * DD];
#pragma unroll
    for (int b = 0; b < 8; ++b) acc[b] += qh[b][r] * w;
  }
#pragma unroll
  for (int b = 0; b < 8; ++b) p[(b * HH + hh) * DD + j0 + threadIdx.x] = acc[b] * INV_SQRT_DH;
  if ((blockIdx.x & 3) == 0 && threadIdx.x < 8) {
    int b = threadIdx.x;
    float cc = 0.0f;
    for (int r = 0; r < 128; ++r) cc += qh[b][r] * in_b[DD + hh * 128 + r];
    c[b * HH + hh] = cc * INV_SQRT_DH;
  }
}

// Big streaming pass: dist[b,t] (f64 acc) and scores[b,h,t]
__global__ __launch_bounds__(256, 4) void k_main(const float* __restrict__ video,
    const float* __restrict__ mu_q, const float* __restrict__ isig,
    const float* __restrict__ p, const float* __restrict__ c,
    float* __restrict__ dist_out, float* __restrict__ scores) {
  __shared__ float s_mu[DD];
  __shared__ float s_is[DD];
  __shared__ float s_p[HH][DD];
  int b = blockIdx.x >> 8;
  int chunk = blockIdx.x & 255;
  int tid = threadIdx.x;
  int wave = tid >> 6, lane = tid & 63;
  // cooperative LDS load
  float4* s_mu4 = (float4*)s_mu;
  float4* s_is4 = (float4*)s_is;
  float4* s_p4 = (float4*)&s_p[0][0];
  s_mu4[tid] = ((const float4*)(mu_q + b * DD))[tid];
  s_is4[tid] = ((const float4*)(isig + b * DD))[tid];
  const float4* pg4 = (const float4*)(p + b * HH * DD);
  for (int i = tid; i < 2048; i += 256) s_p4[i] = pg4[i];
  __syncthreads();

  int t0 = chunk * 16 + wave * 4;
  const float4* v4 = (const float4*)(video + ((size_t)(b * TT + t0)) * DD);
  double dacc[4] = {0.0, 0.0, 0.0, 0.0};
  float sacc[4][8];
#pragma unroll
  for (int t = 0; t < 4; ++t)
#pragma unroll
    for (int hh = 0; hh < 8; ++hh) sacc[t][hh] = 0.0f;

#pragma unroll
  for (int i = 0; i < 4; ++i) {
    int d4 = i * 64 + lane;
    float4 vv[4];
#pragma unroll
    for (int t = 0; t < 4; ++t) vv[t] = v4[t * 256 + d4];
    float4 mu4 = s_mu4[d4];
    float4 is4 = s_is4[d4];
    float4 pp[8];
#pragma unroll
    for (int hh = 0; hh < 8; ++hh) pp[hh] = ((const float4*)&s_p[hh][0])[d4];
#pragma unroll
    for (int t = 0; t < 4; ++t) {
      float dx = vv[t].x - mu4.x;
      float dy = vv[t].y - mu4.y;
      float dz = vv[t].z - mu4.z;
      float dw = vv[t].w - mu4.w;
      float e = dx * dx * is4.x + dy * dy * is4.y + dz * dz * is4.z + dw * dw * is4.w;
      dacc[t] += (double)e;
#pragma unroll
      for (int hh = 0; hh < 8; ++hh)
        sacc[t][hh] += pp[hh].x * vv[t].x + pp[hh].y * vv[t].y +
                       pp[hh].z * vv[t].z + pp[hh].w * vv[t].w;
    }
  }
#pragma unroll
  for (int off = 32; off; off >>= 1) {
#pragma unroll
    for (int t = 0; t < 4; ++t) {
      dacc[t] += __shfl_xor(dacc[t], off, 64);
#pragma unroll
      for (int hh = 0; hh < 8; ++hh) sacc[t][hh] += __shfl_xor(sacc[t][hh], off, 64);
    }
  }
  if (lane == 0) {
#pragma unroll
    for (int t = 0; t < 4; ++t) {
      int tt = t0 + t;
      dist_out[b * TT + tt] = (float)dacc[t];
#pragma unroll
      for (int hh = 0; hh < 8; ++hh)
        scores[(size_t)(b * HH + hh) * TT + tt] = sacc[t][hh] + c[b * HH + hh];
    }
  }
}

// in-place softmax over each (b,h) row of 4096
__global__ __launch_bounds__(256) void k_softmax(float* __restrict__ scores) {
  float* s = scores + (size_t)blockIdx.x * TT;
  __shared__ float buf[TT];
  __shared__ float red[256];
  int tid = threadIdx.x;
  float m = -INFINITY;
  for (int i = tid; i < TT; i += 256) { float v = s[i]; buf[i] = v; m = fmaxf(m, v); }
  red[tid] = m; __syncthreads();
  for (int off = 128; off; off >>= 1) { if (tid < off) red[tid] = fmaxf(red[tid], red[tid + off]); __syncthreads(); }
  float mx = red[0];
  __syncthreads();
  float ps = 0.0f;
  for (int i = tid; i < TT; i += 256) { float e = expf(buf[i] - mx); buf[i] = e; ps += e; }
  red[tid] = ps; __syncthreads();
  for (int off = 128; off; off >>= 1) { if (tid < off) red[tid] += red[tid + off]; __syncthreads(); }
  float inv = 1.0f / red[0];
  for (int i = tid; i < TT; i += 256) s[i] = buf[i] * inv;
}

// per-b: median of dist (bitonic sort in LDS), then combined = dist_w * attn_w
__global__ __launch_bounds__(1024) void k_median(const float* __restrict__ dist,
    const float* __restrict__ attn, float* __restrict__ combined) {
  int b = blockIdx.x;
  __shared__ float s[TT];
  for (int i = threadIdx.x; i < TT; i += 1024) s[i] = dist[b * TT + i];
  __syncthreads();
  for (int k = 2; k <= TT; k <<= 1) {
    for (int j = k >> 1; j > 0; j >>= 1) {
      for (int i = threadIdx.x; i < TT; i += 1024) {
        int ixj = i ^ j;
        if (ixj > i) {
          float a = s[i], c2 = s[ixj];
          bool up = ((i & k) == 0);
          if ((a > c2) == up) { s[i] = c2; s[ixj] = a; }
        }
      }
      __syncthreads();
    }
  }
  float med = s[(TT - 1) / 2];
  for (int i = threadIdx.x; i < TT; i += 1024) {
    float d = dist[b * TT + i];
    float dw = expf(-fabsf(d - med) / 0.1f);
    float aw = 0.0f;
#pragma unroll
    for (int hh = 0; hh < HH; ++hh) aw += attn[(size_t)(b * HH + hh) * TT + i];
    combined[b * TT + i] = dw * (aw * 0.125f);
  }
}

// greedy K-selection per b (matches jnp.argmax first-occurrence semantics)
__global__ __launch_bounds__(256) void k_select(const float* __restrict__ combined,
    float* __restrict__ idx_out, int* __restrict__ idx_ws) {
  int b = blockIdx.x;
  __shared__ float comb[TT];
  __shared__ float mind[TT];
  __shared__ float rv[256];
  __shared__ int ri[256];
  int tid = threadIdx.x;
  for (int i = tid; i < TT; i += 256) comb[i] = combined[b * TT + i];
  __syncthreads();
  int picks[KK];
  for (int k = 0; k < KK; ++k) {
    float best = -INFINITY; int bi = 1 << 30;
    for (int i = tid; i < TT; i += 256) {
      float cv = comb[i];
      float sc = (k == 0) ? cv : ((cv < 0.0f) ? -INFINITY : mind[i] * cv);
      if (sc > best) { best = sc; bi = i; }
    }
    rv[tid] = best; ri[tid] = bi;
    __syncthreads();
    for (int off = 128; off; off >>= 1) {
      if (tid < off) {
        float ov = rv[tid + off]; int oi = ri[tid + off];
        if (ov > rv[tid] || (ov == rv[tid] && oi < ri[tid])) { rv[tid] = ov; ri[tid] = oi; }
      }
      __syncthreads();
    }
    int pick = ri[0];
    picks[k] = pick;
    if (tid == 0) comb[pick] = -1.0f;
    for (int i = tid; i < TT; i += 256) {
      float dnew = fabsf((float)(i - pick));
      mind[i] = (k == 0) ? dnew : fminf(mind[i], dnew);
    }
    __syncthreads();
  }
  if (tid < KK) {
    idx_out[b * KK + tid] = (float)picks[tid];
    idx_ws[b * KK + tid] = picks[tid];
  }
}

// gather rep + loss (ellipsoid + consistency + diversity)
__global__ __launch_bounds__(256) void k_final(const float* __restrict__ video,
    const float* __restrict__ dist, const int* __restrict__ idx,
    float* __restrict__ rep, float* __restrict__ loss_out) {
  __shared__ float repb[KK * DD];
  __shared__ float wdiv[4];
  int tid = threadIdx.x;
  int wave = tid >> 6, lane = tid & 63;
  const int pk[15] = {0,0,0,0,0,1,1,1,1,2,2,2,3,3,4};
  const int pj[15] = {1,2,3,4,5,2,3,4,5,3,4,5,4,5,5};
  float divacc = 0.0f;
  for (int b = 0; b < BD; ++b) {
    for (int e = tid; e < KK * DD; e += 256) {
      int k = e >> 10, d = e & 1023;
      float v = video[((size_t)(b * TT + idx[b * KK + k])) * DD + d];
      rep[(size_t)(b * KK + k) * DD + d] = v;
      repb[e] = v;
    }
    __syncthreads();
    for (int pid = wave; pid < 15; pid += 4) {
      int kk = pk[pid], jj = pj[pid];
      float part = 0.0f;
      for (int d = lane; d < DD; d += 64) part += repb[kk * DD + d] * repb[jj * DD + d];
#pragma unroll
      for (int off = 32; off; off >>= 1) part += __shfl_xor(part, off, 64);
      if (lane == 0) divacc += part * part;
    }
    __syncthreads();
  }
  if (lane == 0) wdiv[wave] = divacc;
  __syncthreads();
  if (tid == 0) {
    float div = (wdiv[0] + wdiv[1] + wdiv[2] + wdiv[3]) / 288.0f;
    float ell = 0.0f, cons = 0.0f;
    for (int b = 0; b < BD; ++b) {
      float rd[KK], srt[KK];
      for (int k = 0; k < KK; ++k) { rd[k] = dist[b * TT + idx[b * KK + k]]; srt[k] = rd[k]; }
      for (int a = 1; a < KK; ++a) {
        float key = srt[a]; int b2 = a - 1;
        while (b2 >= 0 && srt[b2] > key) { srt[b2 + 1] = srt[b2]; --b2; }
        srt[b2 + 1] = key;
      }
      float target = srt[(KK - 1) / 2];
      for (int k = 0; k < KK; ++k) { float d = rd[k] - target; ell += d * d; cons += rd[k]; }
    }
    ell *= (1.0f / 48.0f);
    cons *= (1.0f / 48.0f);
    loss_out[0] = ell + 0.1f * cons + 0.05f * div;
  }
}

extern "C" void kernel_launch(void* const* d_in, const int* in_sizes, int n_in,
                              void* d_out, int out_size, void* d_ws, size_t ws_size,
                              hipStream_t stream) {
  const float* video = (const float*)d_in[0];
  const float* qe    = (const float*)d_in[1];
  const float* mu_w1 = (const float*)d_in[2];
  const float* mu_b1 = (const float*)d_in[3];
  const float* mu_g  = (const float*)d_in[4];
  const float* mu_be = (const float*)d_in[5];
  const float* mu_w2 = (const float*)d_in[6];
  const float* mu_b2 = (const float*)d_in[7];
  const float* sg_w1 = (const float*)d_in[8];
  const float* sg_b1 = (const float*)d_in[9];
  const float* sg_g  = (const float*)d_in[10];
  const float* sg_be = (const float*)d_in[11];
  const float* sg_w2 = (const float*)d_in[12];
  const float* sg_b2 = (const float*)d_in[13];
  const float* in_w  = (const float*)d_in[14];
  const float* in_b  = (const float*)d_in[15];
  float* out = (float*)d_out;
  float* ws  = (float*)d_ws;
  int* idx_ws = (int*)(ws + WS_IDXI);

  k_gemv_pre<<<512, 256, 0, stream>>>(qe, mu_w1, sg_w1, mu_b1, sg_b1, ws + WS_X1);
  k_ln<<<16, 256, 0, stream>>>(ws + WS_X1, mu_g, mu_be, sg_g, sg_be, ws + WS_H);
  k_gemv_mid<<<512, 256, 0, stream>>>(ws + WS_H, mu_w2, sg_w2, mu_b2, sg_b2,
                                      out + OFF_MU, out + OFF_SG, ws + WS_ISIG);
  k_gemv_q<<<256, 256, 0, stream>>>(out + OFF_MU, in_w, in_b, ws + WS_Q);
  k_p<<<32, 256, 0, stream>>>(ws + WS_Q, in_w, in_b, ws + WS_P, ws + WS_C);
  k_main<<<2048, 256, 0, stream>>>(video, out + OFF_MU, ws + WS_ISIG, ws + WS_P, ws + WS_C,
                                   out + OFF_DIST, ws + WS_SCORES);
  k_softmax<<<64, 256, 0, stream>>>(ws + WS_SCORES);
  k_median<<<8, 1024, 0, stream>>>(out + OFF_DIST, ws + WS_SCORES, out + OFF_COMB);
  k_select<<<8, 256, 0, stream>>>(out + OFF_COMB, out + OFF_IDX, idx_ws);
  k_final<<<1, 256, 0, stream>>>(video, out + OFF_DIST, idx_ws, out + OFF_REP, out + OFF_LOSS);
}

// Round 2
// 390.565 us; speedup vs baseline: 1.4508x; 1.4508x over previous
//
#include <hip/hip_runtime.h>
#include <math.h>

// ---------------- problem constants ----------------
#define BD   8       // batch
#define TT   4096    // time
#define DD   1024    // feature dim
#define HH   8       // heads
#define KK   6       // picks
// d_out layout (floats): rep | indices | combined | dist | mu_q | sigma_q | loss
#define OFF_REP   0
#define OFF_IDX   49152
#define OFF_COMB  49200
#define OFF_DIST  81968
#define OFF_MU    114736
#define OFF_SG    122928
#define OFF_LOSS  131120
// ws layout (floats)
#define WS_X1     0        // 2*8*1024
#define WS_H      16384    // 2*8*1024
#define WS_Q      32768    // 8*1024
#define WS_P      40960    // 8*8*1024
#define WS_C      106496   // 64
#define WS_ISIG   106560   // 8*1024
#define WS_SCORES 114752   // 8*8*4096
#define WS_IDXI   376896   // 48 ints

#define INV_SQRT_DH 0.08838834764831845f  // 1/sqrt(128)

__device__ __forceinline__ float softplus_f(float x) {
  return fmaxf(x, 0.0f) + log1pf(expf(-fabsf(x)));
}

// ---- shared GEMV core: out[b,row] = in[b,:] . W[row,:]  (8 batches, wave per row)
__device__ __forceinline__ void gemv_rows_core(const float* __restrict__ in,
                                               const float* __restrict__ W,
                                               int row, float (*s_in)[DD], float acc[8]) {
  int tid = threadIdx.x;
  const float4* in4 = (const float4*)in;
  float4* s4 = (float4*)&s_in[0][0];
  for (int i = tid; i < 2048; i += 256) s4[i] = in4[i];
  __syncthreads();
  int lane = tid & 63;
  const float4* wr4 = (const float4*)(W + (size_t)row * DD);
#pragma unroll
  for (int b = 0; b < 8; ++b) acc[b] = 0.0f;
#pragma unroll
  for (int i = 0; i < 4; ++i) {
    int d4 = i * 64 + lane;
    float4 w4 = wr4[d4];
#pragma unroll
    for (int b = 0; b < 8; ++b) {
      float4 q4 = ((const float4*)&s_in[b][0])[d4];
      acc[b] += w4.x * q4.x + w4.y * q4.y + w4.z * q4.z + w4.w * q4.w;
    }
  }
#pragma unroll
  for (int off = 32; off; off >>= 1)
#pragma unroll
    for (int b = 0; b < 8; ++b) acc[b] += __shfl_xor(acc[b], off, 64);
}

// x1[path][b][row] = qe[b]·W{path}[row] + bias
__global__ __launch_bounds__(256) void k_gemv_pre(const float* __restrict__ qe,
    const float* __restrict__ W0, const float* __restrict__ W1,
    const float* __restrict__ b0, const float* __restrict__ b1, float* __restrict__ x1) {
  __shared__ float s_in[8][DD];
  int path = blockIdx.x >> 8;
  int row = (blockIdx.x & 255) * 4 + (threadIdx.x >> 6);
  const float* W = path ? W1 : W0;
  const float* bb = path ? b1 : b0;
  float acc[8];
  gemv_rows_core(qe, W, row, s_in, acc);
  if ((threadIdx.x & 63) == 0) {
    float bv = bb[row];
#pragma unroll
    for (int b = 0; b < 8; ++b) x1[path * 8192 + b * DD + row] = acc[b] + bv;
  }
}

// LN + relu per (path,b) row of 1024
__global__ __launch_bounds__(256) void k_ln(const float* __restrict__ x1,
    const float* __restrict__ g0, const float* __restrict__ be0,
    const float* __restrict__ g1, const float* __restrict__ be1, float* __restrict__ h) {
  int path = blockIdx.x >> 3, b = blockIdx.x & 7;
  const float* x = x1 + path * 8192 + b * DD;
  const float* g = path ? g1 : g0;
  const float* be = path ? be1 : be0;
  __shared__ float sx[DD];
  __shared__ float red[256];
  int tid = threadIdx.x;
  float ps = 0.0f;
  for (int i = tid; i < DD; i += 256) { float v = x[i]; sx[i] = v; ps += v; }
  red[tid] = ps; __syncthreads();
  for (int off = 128; off; off >>= 1) { if (tid < off) red[tid] += red[tid + off]; __syncthreads(); }
  float mean = red[0] * (1.0f / 1024.0f);
  __syncthreads();
  float pv = 0.0f;
  for (int i = tid; i < DD; i += 256) { float d = sx[i] - mean; pv += d * d; }
  red[tid] = pv; __syncthreads();
  for (int off = 128; off; off >>= 1) { if (tid < off) red[tid] += red[tid + off]; __syncthreads(); }
  float var = red[0] * (1.0f / 1024.0f);
  float inv = 1.0f / sqrtf(var + 1e-5f);
  for (int i = tid; i < DD; i += 256) {
    float v = (sx[i] - mean) * inv * g[i] + be[i];
    h[path * 8192 + b * DD + i] = v > 0.0f ? v : 0.0f;
  }
}

// path0: mu_q; path1: sigma_q = softplus+1e-6, isig = 1/sigma
__global__ __launch_bounds__(256) void k_gemv_mid(const float* __restrict__ h,
    const float* __restrict__ W0, const float* __restrict__ W1,
    const float* __restrict__ b0, const float* __restrict__ b1,
    float* __restrict__ mu_out, float* __restrict__ sg_out, float* __restrict__ isig) {
  __shared__ float s_in[8][DD];
  int path = blockIdx.x >> 8;
  int row = (blockIdx.x & 255) * 4 + (threadIdx.x >> 6);
  const float* W = path ? W1 : W0;
  const float* bb = path ? b1 : b0;
  float acc[8];
  gemv_rows_core(h + path * 8192, W, row, s_in, acc);
  if ((threadIdx.x & 63) == 0) {
    float bv = bb[row];
#pragma unroll
    for (int b = 0; b < 8; ++b) {
      float v = acc[b] + bv;
      if (path == 0) {
        mu_out[b * DD + row] = v;
      } else {
        float sp = softplus_f(v) + 1e-6f;
        sg_out[b * DD + row] = sp;
        isig[b * DD + row] = 1.0f / sp;
      }
    }
  }
}

// q[b,row] = mu_q[b]·wq[row] + bq[row]   (wq = in_w rows 0..1023)
__global__ __launch_bounds__(256) void k_gemv_q(const float* __restrict__ mu_q,
    const float* __restrict__ in_w, const float* __restrict__ in_b, float* __restrict__ q) {
  __shared__ float s_in[8][DD];
  int row = blockIdx.x * 4 + (threadIdx.x >> 6);
  float acc[8];
  gemv_rows_core(mu_q, in_w, row, s_in, acc);
  if ((threadIdx.x & 63) == 0) {
    float bv = in_b[row];
#pragma unroll
    for (int b = 0; b < 8; ++b) q[b * DD + row] = acc[b] + bv;
  }
}

// p[b,h,j] = (sum_r q[b,h*128+r]*wk[h*128+r,j]) / sqrt(128);  c[b,h] analog with bk
__global__ __launch_bounds__(256) void k_p(const float* __restrict__ q,
    const float* __restrict__ in_w, const float* __restrict__ in_b,
    float* __restrict__ p, float* __restrict__ c) {
  int hh = blockIdx.x >> 2;
  int j0 = (blockIdx.x & 3) * 256;
  __shared__ float qh[8][128];
  for (int i = threadIdx.x; i < 1024; i += 256) {
    int b = i >> 7, r = i & 127;
    qh[b][r] = q[b * DD + hh * 128 + r];
  }
  __syncthreads();
  const float* wbase = in_w + (size_t)(DD + hh * 128) * DD + j0 + threadIdx.x;
  float acc[8];
#pragma unroll
  for (int b = 0; b < 8; ++b) acc[b] = 0.0f;
  for (int r = 0; r < 128; ++r) {
    float w = wbase[(size_t)r * DD];
#pragma unroll
    for (int b = 0; b < 8; ++b) acc[b] += qh[b][r] * w;
  }
#pragma unroll
  for (int b = 0; b < 8; ++b) p[(b * HH + hh) * DD + j0 + threadIdx.x] = acc[b] * INV_SQRT_DH;
  if ((blockIdx.x & 3) == 0 && threadIdx.x < 8) {
    int b = threadIdx.x;
    float cc = 0.0f;
    for (int r = 0; r < 128; ++r) cc += qh[b][r] * in_b[DD + hh * 128 + r];
    c[b * HH + hh] = cc * INV_SQRT_DH;
  }
}

// Big streaming pass: dist[b,t] (f64 acc) and scores[b,h,t]
// Restructured vs R1: single transient pp float4 (hh loop innermost) to keep
// live VGPRs ~80 < 128 cap -> no scratch spill (R1 spilled 400+ MB).
__global__ __launch_bounds__(256, 4) void k_main(const float* __restrict__ video,
    const float* __restrict__ mu_q, const float* __restrict__ isig,
    const float* __restrict__ p, const float* __restrict__ c,
    float* __restrict__ dist_out, float* __restrict__ scores) {
  __shared__ float s_mu[DD];
  __shared__ float s_is[DD];
  __shared__ float s_p[HH][DD];
  int b = blockIdx.x >> 8;
  int chunk = blockIdx.x & 255;
  int tid = threadIdx.x;
  int wave = tid >> 6, lane = tid & 63;
  float4* s_mu4 = (float4*)s_mu;
  float4* s_is4 = (float4*)s_is;
  float4* s_p4 = (float4*)&s_p[0][0];
  s_mu4[tid] = ((const float4*)(mu_q + b * DD))[tid];
  s_is4[tid] = ((const float4*)(isig + b * DD))[tid];
  const float4* pg4 = (const float4*)(p + b * HH * DD);
  for (int i = tid; i < 2048; i += 256) s_p4[i] = pg4[i];
  __syncthreads();

  int t0 = chunk * 16 + wave * 4;
  const float4* v4 = (const float4*)(video + ((size_t)(b * TT + t0)) * DD);
  double dacc[4] = {0.0, 0.0, 0.0, 0.0};
  float sacc[4][8];
#pragma unroll
  for (int t = 0; t < 4; ++t)
#pragma unroll
    for (int hh = 0; hh < 8; ++hh) sacc[t][hh] = 0.0f;

#pragma unroll 2
  for (int i = 0; i < 4; ++i) {
    int d4 = i * 64 + lane;
    float4 vv0 = v4[0 * 256 + d4];
    float4 vv1 = v4[1 * 256 + d4];
    float4 vv2 = v4[2 * 256 + d4];
    float4 vv3 = v4[3 * 256 + d4];
    {
      float4 mu4 = s_mu4[d4];
      float4 is4 = s_is4[d4];
      float dx, dy, dz, dw, e;
      dx = vv0.x - mu4.x; dy = vv0.y - mu4.y; dz = vv0.z - mu4.z; dw = vv0.w - mu4.w;
      e = dx * dx * is4.x + dy * dy * is4.y + dz * dz * is4.z + dw * dw * is4.w;
      dacc[0] += (double)e;
      dx = vv1.x - mu4.x; dy = vv1.y - mu4.y; dz = vv1.z - mu4.z; dw = vv1.w - mu4.w;
      e = dx * dx * is4.x + dy * dy * is4.y + dz * dz * is4.z + dw * dw * is4.w;
      dacc[1] += (double)e;
      dx = vv2.x - mu4.x; dy = vv2.y - mu4.y; dz = vv2.z - mu4.z; dw = vv2.w - mu4.w;
      e = dx * dx * is4.x + dy * dy * is4.y + dz * dz * is4.z + dw * dw * is4.w;
      dacc[2] += (double)e;
      dx = vv3.x - mu4.x; dy = vv3.y - mu4.y; dz = vv3.z - mu4.z; dw = vv3.w - mu4.w;
      e = dx * dx * is4.x + dy * dy * is4.y + dz * dz * is4.z + dw * dw * is4.w;
      dacc[3] += (double)e;
    }
#pragma unroll
    for (int hh = 0; hh < 8; ++hh) {
      float4 pp = ((const float4*)&s_p[hh][0])[d4];
      sacc[0][hh] += pp.x * vv0.x + pp.y * vv0.y + pp.z * vv0.z + pp.w * vv0.w;
      sacc[1][hh] += pp.x * vv1.x + pp.y * vv1.y + pp.z * vv1.z + pp.w * vv1.w;
      sacc[2][hh] += pp.x * vv2.x + pp.y * vv2.y + pp.z * vv2.z + pp.w * vv2.w;
      sacc[3][hh] += pp.x * vv3.x + pp.y * vv3.y + pp.z * vv3.z + pp.w * vv3.w;
    }
  }
  // butterfly: afterwards ALL lanes hold the full sums
#pragma unroll
  for (int off = 32; off; off >>= 1) {
#pragma unroll
    for (int t = 0; t < 4; ++t) {
      dacc[t] += __shfl_xor(dacc[t], off, 64);
#pragma unroll
      for (int hh = 0; hh < 8; ++hh) sacc[t][hh] += __shfl_xor(sacc[t][hh], off, 64);
    }
  }
  if (lane < 4) {
    int t = lane;
    int tt = t0 + t;
    dist_out[b * TT + tt] = (float)dacc[t];
#pragma unroll
    for (int hh = 0; hh < 8; ++hh)
      scores[(size_t)(b * HH + hh) * TT + tt] = sacc[t][hh] + c[b * HH + hh];
  }
}

// in-place softmax over each (b,h) row of 4096
__global__ __launch_bounds__(256) void k_softmax(float* __restrict__ scores) {
  float* s = scores + (size_t)blockIdx.x * TT;
  __shared__ float buf[TT];
  __shared__ float red[256];
  int tid = threadIdx.x;
  float m = -INFINITY;
  for (int i = tid; i < TT; i += 256) { float v = s[i]; buf[i] = v; m = fmaxf(m, v); }
  red[tid] = m; __syncthreads();
  for (int off = 128; off; off >>= 1) { if (tid < off) red[tid] = fmaxf(red[tid], red[tid + off]); __syncthreads(); }
  float mx = red[0];
  __syncthreads();
  float ps = 0.0f;
  for (int i = tid; i < TT; i += 256) { float e = expf(buf[i] - mx); buf[i] = e; ps += e; }
  red[tid] = ps; __syncthreads();
  for (int off = 128; off; off >>= 1) { if (tid < off) red[tid] += red[tid + off]; __syncthreads(); }
  float inv = 1.0f / red[0];
  for (int i = tid; i < TT; i += 256) s[i] = buf[i] * inv;
}

// per-b: median of dist (bitonic sort in LDS), then combined = dist_w * attn_w
__global__ __launch_bounds__(1024) void k_median(const float* __restrict__ dist,
    const float* __restrict__ attn, float* __restrict__ combined) {
  int b = blockIdx.x;
  __shared__ float s[TT];
  for (int i = threadIdx.x; i < TT; i += 1024) s[i] = dist[b * TT + i];
  __syncthreads();
  for (int k = 2; k <= TT; k <<= 1) {
    for (int j = k >> 1; j > 0; j >>= 1) {
      for (int i = threadIdx.x; i < TT; i += 1024) {
        int ixj = i ^ j;
        if (ixj > i) {
          float a = s[i], c2 = s[ixj];
          bool up = ((i & k) == 0);
          if ((a > c2) == up) { s[i] = c2; s[ixj] = a; }
        }
      }
      __syncthreads();
    }
  }
  float med = s[(TT - 1) / 2];
  for (int i = threadIdx.x; i < TT; i += 1024) {
    float d = dist[b * TT + i];
    float dw = expf(-fabsf(d - med) / 0.1f);
    float aw = 0.0f;
#pragma unroll
    for (int hh = 0; hh < HH; ++hh) aw += attn[(size_t)(b * HH + hh) * TT + i];
    combined[b * TT + i] = dw * (aw * 0.125f);
  }
}

// greedy K-selection per b (matches jnp.argmax first-occurrence semantics)
// wave-shuffle argmax reduction: 2 barriers per pick instead of 8
__global__ __launch_bounds__(256) void k_select(const float* __restrict__ combined,
    float* __restrict__ idx_out, int* __restrict__ idx_ws, float* __restrict__ loss_out) {
  int b = blockIdx.x;
  int tid = threadIdx.x;
  int wave = tid >> 6, lane = tid & 63;
  if (b == 0 && tid == 0) loss_out[0] = 0.0f;  // k_final (stream-ordered after) accumulates
  __shared__ float comb[TT];
  __shared__ float mind[TT];
  __shared__ float wv[4];
  __shared__ int wi[4];
  __shared__ int s_pick;
  for (int i = tid; i < TT; i += 256) comb[i] = combined[b * TT + i];
  __syncthreads();
  int picks[KK];
  for (int k = 0; k < KK; ++k) {
    float best = -INFINITY; int bi = 1 << 30;
    for (int i = tid; i < TT; i += 256) {
      float cv = comb[i];
      float sc = (k == 0) ? cv : ((cv < 0.0f) ? -INFINITY : mind[i] * cv);
      if (sc > best) { best = sc; bi = i; }
    }
#pragma unroll
    for (int off = 32; off; off >>= 1) {
      float ov = __shfl_xor(best, off, 64);
      int oi = __shfl_xor(bi, off, 64);
      if (ov > best || (ov == best && oi < bi)) { best = ov; bi = oi; }
    }
    if (lane == 0) { wv[wave] = best; wi[wave] = bi; }
    __syncthreads();
    if (tid == 0) {
      float bb2 = wv[0]; int ii = wi[0];
#pragma unroll
      for (int w = 1; w < 4; ++w)
        if (wv[w] > bb2 || (wv[w] == bb2 && wi[w] < ii)) { bb2 = wv[w]; ii = wi[w]; }
      s_pick = ii;
      comb[ii] = -1.0f;
    }
    __syncthreads();
    int pick = s_pick;
    picks[k] = pick;
    for (int i = tid; i < TT; i += 256) {
      float dnew = fabsf((float)(i - pick));
      mind[i] = (k == 0) ? dnew : fminf(mind[i], dnew);
    }
    // no barrier needed: mind[i] is self-owned per thread; comb[pick] synced above
  }
  if (tid < KK) {
    idx_out[b * KK + tid] = (float)picks[tid];
    idx_ws[b * KK + tid] = picks[tid];
  }
}

// gather rep + loss, parallel over batch (8 blocks); atomicAdd partials
__global__ __launch_bounds__(256) void k_final(const float* __restrict__ video,
    const float* __restrict__ dist, const int* __restrict__ idx,
    float* __restrict__ rep, float* __restrict__ loss_out) {
  int b = blockIdx.x;
  __shared__ float repb[KK * DD];
  __shared__ float wdiv[4];
  __shared__ float s_rd[KK];
  int tid = threadIdx.x;
  int wave = tid >> 6, lane = tid & 63;
  const int pk[15] = {0,0,0,0,0,1,1,1,1,2,2,2,3,3,4};
  const int pj[15] = {1,2,3,4,5,2,3,4,5,3,4,5,4,5,5};
  // gather rows (float4)
  float4* repb4 = (float4*)repb;
  float4* rep4 = (float4*)(rep + (size_t)b * KK * DD);
  for (int e = tid; e < KK * (DD / 4); e += 256) {
    int k = e >> 8, d4 = e & 255;
    const float4* vrow = (const float4*)(video + ((size_t)(b * TT + idx[b * KK + k])) * DD);
    float4 v = vrow[d4];
    rep4[(size_t)k * (DD / 4) + d4] = v;
    repb4[k * (DD / 4) + d4] = v;
  }
  if (tid < KK) s_rd[tid] = dist[b * TT + idx[b * KK + tid]];
  __syncthreads();
  float divacc = 0.0f;
  for (int pid = wave; pid < 15; pid += 4) {
    int kk = pk[pid], jj = pj[pid];
    float part = 0.0f;
    for (int d = lane; d < DD; d += 64) part += repb[kk * DD + d] * repb[jj * DD + d];
#pragma unroll
    for (int off = 32; off; off >>= 1) part += __shfl_xor(part, off, 64);
    if (lane == 0) divacc += part * part;
  }
  if (lane == 0) wdiv[wave] = divacc;
  __syncthreads();
  if (tid == 0) {
    float div = wdiv[0] + wdiv[1] + wdiv[2] + wdiv[3];
    float rd[KK], srt[KK];
#pragma unroll
    for (int k = 0; k < KK; ++k) { rd[k] = s_rd[k]; srt[k] = rd[k]; }
    for (int a = 1; a < KK; ++a) {
      float key = srt[a]; int b2 = a - 1;
      while (b2 >= 0 && srt[b2] > key) { srt[b2 + 1] = srt[b2]; --b2; }
      srt[b2 + 1] = key;
    }
    float target = srt[(KK - 1) / 2];
    float ell = 0.0f, cons = 0.0f;
#pragma unroll
    for (int k = 0; k < KK; ++k) { float d = rd[k] - target; ell += d * d; cons += rd[k]; }
    float partial = ell * (1.0f / 48.0f) + 0.1f * cons * (1.0f / 48.0f) + 0.05f * div * (1.0f / 288.0f);
    atomicAdd(loss_out, partial);
  }
}

extern "C" void kernel_launch(void* const* d_in, const int* in_sizes, int n_in,
                              void* d_out, int out_size, void* d_ws, size_t ws_size,
                              hipStream_t stream) {
  const float* video = (const float*)d_in[0];
  const float* qe    = (const float*)d_in[1];
  const float* mu_w1 = (const float*)d_in[2];
  const float* mu_b1 = (const float*)d_in[3];
  const float* mu_g  = (const float*)d_in[4];
  const float* mu_be = (const float*)d_in[5];
  const float* mu_w2 = (const float*)d_in[6];
  const float* mu_b2 = (const float*)d_in[7];
  const float* sg_w1 = (const float*)d_in[8];
  const float* sg_b1 = (const float*)d_in[9];
  const float* sg_g  = (const float*)d_in[10];
  const float* sg_be = (const float*)d_in[11];
  const float* sg_w2 = (const float*)d_in[12];
  const float* sg_b2 = (const float*)d_in[13];
  const float* in_w  = (const float*)d_in[14];
  const float* in_b  = (const float*)d_in[15];
  float* out = (float*)d_out;
  float* ws  = (float*)d_ws;
  int* idx_ws = (int*)(ws + WS_IDXI);

  k_gemv_pre<<<512, 256, 0, stream>>>(qe, mu_w1, sg_w1, mu_b1, sg_b1, ws + WS_X1);
  k_ln<<<16, 256, 0, stream>>>(ws + WS_X1, mu_g, mu_be, sg_g, sg_be, ws + WS_H);
  k_gemv_mid<<<512, 256, 0, stream>>>(ws + WS_H, mu_w2, sg_w2, mu_b2, sg_b2,
                                      out + OFF_MU, out + OFF_SG, ws + WS_ISIG);
  k_gemv_q<<<256, 256, 0, stream>>>(out + OFF_MU, in_w, in_b, ws + WS_Q);
  k_p<<<32, 256, 0, stream>>>(ws + WS_Q, in_w, in_b, ws + WS_P, ws + WS_C);
  k_main<<<2048, 256, 0, stream>>>(video, out + OFF_MU, ws + WS_ISIG, ws + WS_P, ws + WS_C,
                                   out + OFF_DIST, ws + WS_SCORES);
  k_softmax<<<64, 256, 0, stream>>>(ws + WS_SCORES);
  k_median<<<8, 1024, 0, stream>>>(out + OFF_DIST, ws + WS_SCORES, out + OFF_COMB);
  k_select<<<8, 256, 0, stream>>>(out + OFF_COMB, out + OFF_IDX, idx_ws, out + OFF_LOSS);
  k_final<<<8, 256, 0, stream>>>(video, out + OFF_DIST, idx_ws, out + OFF_REP, out + OFF_LOSS);
}

// Round 3
// 380.679 us; speedup vs baseline: 1.4885x; 1.0260x over previous
//
#include <hip/hip_runtime.h>
#include <math.h>

// ---------------- problem constants ----------------
#define BD   8       // batch
#define TT   4096    // time
#define DD   1024    // feature dim
#define HH   8       // heads
#define KK   6       // picks
// d_out layout (floats): rep | indices | combined | dist | mu_q | sigma_q | loss
#define OFF_REP   0
#define OFF_IDX   49152
#define OFF_COMB  49200
#define OFF_DIST  81968
#define OFF_MU    114736
#define OFF_SG    122928
#define OFF_LOSS  131120
// ws layout (floats)
#define WS_X1     0        // 2*8*1024
#define WS_H      16384    // 2*8*1024
#define WS_Q      32768    // 8*1024
#define WS_P      40960    // 8*8*1024
#define WS_C      106496   // 64
#define WS_ISIG   106560   // 8*1024
#define WS_SCORES 114752   // 8*8*4096

#define INV_SQRT_DH 0.08838834764831845f  // 1/sqrt(128)

__device__ __forceinline__ float softplus_f(float x) {
  return fmaxf(x, 0.0f) + log1pf(expf(-fabsf(x)));
}

// ---- shared GEMV core: out[b,row] = in[b,:] . W[row,:]  (8 batches, wave per row)
__device__ __forceinline__ void gemv_rows_core(const float* __restrict__ in,
                                               const float* __restrict__ W,
                                               int row, float (*s_in)[DD], float acc[8]) {
  int tid = threadIdx.x;
  const float4* in4 = (const float4*)in;
  float4* s4 = (float4*)&s_in[0][0];
  for (int i = tid; i < 2048; i += 256) s4[i] = in4[i];
  __syncthreads();
  int lane = tid & 63;
  const float4* wr4 = (const float4*)(W + (size_t)row * DD);
#pragma unroll
  for (int b = 0; b < 8; ++b) acc[b] = 0.0f;
#pragma unroll
  for (int i = 0; i < 4; ++i) {
    int d4 = i * 64 + lane;
    float4 w4 = wr4[d4];
#pragma unroll
    for (int b = 0; b < 8; ++b) {
      float4 q4 = ((const float4*)&s_in[b][0])[d4];
      acc[b] += w4.x * q4.x + w4.y * q4.y + w4.z * q4.z + w4.w * q4.w;
    }
  }
#pragma unroll
  for (int off = 32; off; off >>= 1)
#pragma unroll
    for (int b = 0; b < 8; ++b) acc[b] += __shfl_xor(acc[b], off, 64);
}

// x1[path][b][row] = qe[b]·W{path}[row] + bias
__global__ __launch_bounds__(256) void k_gemv_pre(const float* __restrict__ qe,
    const float* __restrict__ W0, const float* __restrict__ W1,
    const float* __restrict__ b0, const float* __restrict__ b1, float* __restrict__ x1) {
  __shared__ float s_in[8][DD];
  int path = blockIdx.x >> 8;
  int row = (blockIdx.x & 255) * 4 + (threadIdx.x >> 6);
  const float* W = path ? W1 : W0;
  const float* bb = path ? b1 : b0;
  float acc[8];
  gemv_rows_core(qe, W, row, s_in, acc);
  if ((threadIdx.x & 63) == 0) {
    float bv = bb[row];
#pragma unroll
    for (int b = 0; b < 8; ++b) x1[path * 8192 + b * DD + row] = acc[b] + bv;
  }
}

// LN + relu per (path,b) row of 1024
__global__ __launch_bounds__(256) void k_ln(const float* __restrict__ x1,
    const float* __restrict__ g0, const float* __restrict__ be0,
    const float* __restrict__ g1, const float* __restrict__ be1, float* __restrict__ h) {
  int path = blockIdx.x >> 3, b = blockIdx.x & 7;
  const float* x = x1 + path * 8192 + b * DD;
  const float* g = path ? g1 : g0;
  const float* be = path ? be1 : be0;
  __shared__ float sx[DD];
  __shared__ float red[256];
  int tid = threadIdx.x;
  float ps = 0.0f;
  for (int i = tid; i < DD; i += 256) { float v = x[i]; sx[i] = v; ps += v; }
  red[tid] = ps; __syncthreads();
  for (int off = 128; off; off >>= 1) { if (tid < off) red[tid] += red[tid + off]; __syncthreads(); }
  float mean = red[0] * (1.0f / 1024.0f);
  __syncthreads();
  float pv = 0.0f;
  for (int i = tid; i < DD; i += 256) { float d = sx[i] - mean; pv += d * d; }
  red[tid] = pv; __syncthreads();
  for (int off = 128; off; off >>= 1) { if (tid < off) red[tid] += red[tid + off]; __syncthreads(); }
  float var = red[0] * (1.0f / 1024.0f);
  float inv = 1.0f / sqrtf(var + 1e-5f);
  for (int i = tid; i < DD; i += 256) {
    float v = (sx[i] - mean) * inv * g[i] + be[i];
    h[path * 8192 + b * DD + i] = v > 0.0f ? v : 0.0f;
  }
}

// path0: mu_q; path1: sigma_q = softplus+1e-6, isig = 1/sigma
__global__ __launch_bounds__(256) void k_gemv_mid(const float* __restrict__ h,
    const float* __restrict__ W0, const float* __restrict__ W1,
    const float* __restrict__ b0, const float* __restrict__ b1,
    float* __restrict__ mu_out, float* __restrict__ sg_out, float* __restrict__ isig) {
  __shared__ float s_in[8][DD];
  int path = blockIdx.x >> 8;
  int row = (blockIdx.x & 255) * 4 + (threadIdx.x >> 6);
  const float* W = path ? W1 : W0;
  const float* bb = path ? b1 : b0;
  float acc[8];
  gemv_rows_core(h + path * 8192, W, row, s_in, acc);
  if ((threadIdx.x & 63) == 0) {
    float bv = bb[row];
#pragma unroll
    for (int b = 0; b < 8; ++b) {
      float v = acc[b] + bv;
      if (path == 0) {
        mu_out[b * DD + row] = v;
      } else {
        float sp = softplus_f(v) + 1e-6f;
        sg_out[b * DD + row] = sp;
        isig[b * DD + row] = 1.0f / sp;
      }
    }
  }
}

// q[b,row] = mu_q[b]·wq[row] + bq[row]   (wq = in_w rows 0..1023)
__global__ __launch_bounds__(256) void k_gemv_q(const float* __restrict__ mu_q,
    const float* __restrict__ in_w, const float* __restrict__ in_b, float* __restrict__ q) {
  __shared__ float s_in[8][DD];
  int row = blockIdx.x * 4 + (threadIdx.x >> 6);
  float acc[8];
  gemv_rows_core(mu_q, in_w, row, s_in, acc);
  if ((threadIdx.x & 63) == 0) {
    float bv = in_b[row];
#pragma unroll
    for (int b = 0; b < 8; ++b) q[b * DD + row] = acc[b] + bv;
  }
}

// p[b,h,j] = (sum_r q[b,h*128+r]*wk[h*128+r,j]) / sqrt(128);  c[b,h] analog with bk
__global__ __launch_bounds__(256) void k_p(const float* __restrict__ q,
    const float* __restrict__ in_w, const float* __restrict__ in_b,
    float* __restrict__ p, float* __restrict__ c) {
  int hh = blockIdx.x >> 2;
  int j0 = (blockIdx.x & 3) * 256;
  __shared__ float qh[8][128];
  for (int i = threadIdx.x; i < 1024; i += 256) {
    int b = i >> 7, r = i & 127;
    qh[b][r] = q[b * DD + hh * 128 + r];
  }
  __syncthreads();
  const float* wbase = in_w + (size_t)(DD + hh * 128) * DD + j0 + threadIdx.x;
  float acc[8];
#pragma unroll
  for (int b = 0; b < 8; ++b) acc[b] = 0.0f;
  for (int r = 0; r < 128; ++r) {
    float w = wbase[(size_t)r * DD];
#pragma unroll
    for (int b = 0; b < 8; ++b) acc[b] += qh[b][r] * w;
  }
#pragma unroll
  for (int b = 0; b < 8; ++b) p[(b * HH + hh) * DD + j0 + threadIdx.x] = acc[b] * INV_SQRT_DH;
  if ((blockIdx.x & 3) == 0 && threadIdx.x < 8) {
    int b = threadIdx.x;
    float cc = 0.0f;
    for (int r = 0; r < 128; ++r) cc += qh[b][r] * in_b[DD + hh * 128 + r];
    c[b * HH + hh] = cc * INV_SQRT_DH;
  }
}

// Big streaming pass: dist[b,t] (f64 acc) and scores[b,h,t]
// Live VGPRs kept ~80 < 128 cap (launch_bounds 256,4) -> no scratch spill.
__global__ __launch_bounds__(256, 4) void k_main(const float* __restrict__ video,
    const float* __restrict__ mu_q, const float* __restrict__ isig,
    const float* __restrict__ p, const float* __restrict__ c,
    float* __restrict__ dist_out, float* __restrict__ scores, float* __restrict__ loss_out) {
  __shared__ float s_mu[DD];
  __shared__ float s_is[DD];
  __shared__ float s_p[HH][DD];
  int b = blockIdx.x >> 8;
  int chunk = blockIdx.x & 255;
  int tid = threadIdx.x;
  int wave = tid >> 6, lane = tid & 63;
  if (blockIdx.x == 0 && tid == 0) loss_out[0] = 0.0f;  // k_epilogue (stream-ordered after) accumulates
  float4* s_mu4 = (float4*)s_mu;
  float4* s_is4 = (float4*)s_is;
  float4* s_p4 = (float4*)&s_p[0][0];
  s_mu4[tid] = ((const float4*)(mu_q + b * DD))[tid];
  s_is4[tid] = ((const float4*)(isig + b * DD))[tid];
  const float4* pg4 = (const float4*)(p + b * HH * DD);
  for (int i = tid; i < 2048; i += 256) s_p4[i] = pg4[i];
  __syncthreads();

  int t0 = chunk * 16 + wave * 4;
  const float4* v4 = (const float4*)(video + ((size_t)(b * TT + t0)) * DD);
  double dacc[4] = {0.0, 0.0, 0.0, 0.0};
  float sacc[4][8];
#pragma unroll
  for (int t = 0; t < 4; ++t)
#pragma unroll
    for (int hh = 0; hh < 8; ++hh) sacc[t][hh] = 0.0f;

#pragma unroll 2
  for (int i = 0; i < 4; ++i) {
    int d4 = i * 64 + lane;
    float4 vv0 = v4[0 * 256 + d4];
    float4 vv1 = v4[1 * 256 + d4];
    float4 vv2 = v4[2 * 256 + d4];
    float4 vv3 = v4[3 * 256 + d4];
    {
      float4 mu4 = s_mu4[d4];
      float4 is4 = s_is4[d4];
      float dx, dy, dz, dw, e;
      dx = vv0.x - mu4.x; dy = vv0.y - mu4.y; dz = vv0.z - mu4.z; dw = vv0.w - mu4.w;
      e = dx * dx * is4.x + dy * dy * is4.y + dz * dz * is4.z + dw * dw * is4.w;
      dacc[0] += (double)e;
      dx = vv1.x - mu4.x; dy = vv1.y - mu4.y; dz = vv1.z - mu4.z; dw = vv1.w - mu4.w;
      e = dx * dx * is4.x + dy * dy * is4.y + dz * dz * is4.z + dw * dw * is4.w;
      dacc[1] += (double)e;
      dx = vv2.x - mu4.x; dy = vv2.y - mu4.y; dz = vv2.z - mu4.z; dw = vv2.w - mu4.w;
      e = dx * dx * is4.x + dy * dy * is4.y + dz * dz * is4.z + dw * dw * is4.w;
      dacc[2] += (double)e;
      dx = vv3.x - mu4.x; dy = vv3.y - mu4.y; dz = vv3.z - mu4.z; dw = vv3.w - mu4.w;
      e = dx * dx * is4.x + dy * dy * is4.y + dz * dz * is4.z + dw * dw * is4.w;
      dacc[3] += (double)e;
    }
#pragma unroll
    for (int hh = 0; hh < 8; ++hh) {
      float4 pp = ((const float4*)&s_p[hh][0])[d4];
      sacc[0][hh] += pp.x * vv0.x + pp.y * vv0.y + pp.z * vv0.z + pp.w * vv0.w;
      sacc[1][hh] += pp.x * vv1.x + pp.y * vv1.y + pp.z * vv1.z + pp.w * vv1.w;
      sacc[2][hh] += pp.x * vv2.x + pp.y * vv2.y + pp.z * vv2.z + pp.w * vv2.w;
      sacc[3][hh] += pp.x * vv3.x + pp.y * vv3.y + pp.z * vv3.z + pp.w * vv3.w;
    }
  }
#pragma unroll
  for (int off = 32; off; off >>= 1) {
#pragma unroll
    for (int t = 0; t < 4; ++t) {
      dacc[t] += __shfl_xor(dacc[t], off, 64);
#pragma unroll
      for (int hh = 0; hh < 8; ++hh) sacc[t][hh] += __shfl_xor(sacc[t][hh], off, 64);
    }
  }
  if (lane < 4) {
    int t = lane;
    int tt = t0 + t;
    dist_out[b * TT + tt] = (float)dacc[t];
#pragma unroll
    for (int hh = 0; hh < 8; ++hh)
      scores[(size_t)(b * HH + hh) * TT + tt] = sacc[t][hh] + c[b * HH + hh];
  }
}

// Fused epilogue, one block per b:
//   softmax stats -> attn mean -> radix-select median -> combined -> greedy-K
//   -> gather rep -> loss partial (atomicAdd; zeroed by k_main).
__global__ __launch_bounds__(256) void k_epilogue(const float* __restrict__ scores,
    const float* __restrict__ dist, const float* __restrict__ video,
    float* __restrict__ comb_out, float* __restrict__ idx_out,
    float* __restrict__ rep, float* __restrict__ loss_out) {
  int b = blockIdx.x;
  int tid = threadIdx.x;
  int wave = tid >> 6, lane = tid & 63;
  __shared__ float s_aw[TT];    // attn mean
  __shared__ float s_comb[TT];  // combined
  __shared__ float s_mind[TT];  // min |i-pick|
  __shared__ float s_dist[TT];
  __shared__ float s_hm[HH], s_hs[HH];
  __shared__ unsigned hist[256];
  __shared__ unsigned wsum[4];
  __shared__ unsigned s_sel;
  __shared__ int s_kk;
  __shared__ float wv[4];
  __shared__ int wi[4];
  __shared__ int s_pick;
  __shared__ float wdiv[4];

  // pass 1: per-head max & inv-sum-exp (32 threads per head; shfl_xor<32 stays in-group)
  {
    int h = tid >> 5, lt = tid & 31;
    const float* srow = scores + ((size_t)(b * HH + h)) * TT;
    float m = -INFINITY;
    for (int i = lt; i < TT; i += 32) m = fmaxf(m, srow[i]);
#pragma unroll
    for (int off = 16; off; off >>= 1) m = fmaxf(m, __shfl_xor(m, off, 64));
    float s = 0.0f;
    for (int i = lt; i < TT; i += 32) s += expf(srow[i] - m);
#pragma unroll
    for (int off = 16; off; off >>= 1) s += __shfl_xor(s, off, 64);
    if (lt == 0) { s_hm[h] = m; s_hs[h] = 1.0f / s; }
  }
  __syncthreads();
  // pass 2: attn mean + stage dist
  for (int i = tid; i < TT; i += 256) {
    float aw = 0.0f;
#pragma unroll
    for (int h = 0; h < HH; ++h)
      aw += expf(scores[((size_t)(b * HH + h)) * TT + i] - s_hm[h]) * s_hs[h];
    s_aw[i] = aw * 0.125f;
    s_dist[i] = dist[b * TT + i];
  }
  __syncthreads();

  // radix-select median: rank 2047 of positive floats (bit pattern is order-isomorphic)
  unsigned prefix = 0;
  int kk = (TT - 1) / 2;
  for (int pass = 0; pass < 4; ++pass) {
    int shift = 24 - 8 * pass;
    hist[tid] = 0;
    __syncthreads();
    for (int i = tid; i < TT; i += 256) {
      unsigned key = __float_as_uint(s_dist[i]);
      bool ok = (pass == 0) || ((key >> (shift + 8)) == prefix);
      if (ok) atomicAdd(&hist[(key >> shift) & 255], 1u);
    }
    __syncthreads();
    unsigned h = hist[tid];
    unsigned inc = h;
#pragma unroll
    for (int off = 1; off < 64; off <<= 1) {
      unsigned v = __shfl_up(inc, off, 64);
      if (lane >= off) inc += v;
    }
    if (lane == 63) wsum[wave] = inc;
    __syncthreads();
    unsigned base = 0;
    for (int w = 0; w < wave; ++w) base += wsum[w];
    unsigned excl = base + inc - h;
    if ((int)excl <= kk && kk < (int)(excl + h)) { s_sel = (prefix << 8) | (unsigned)tid; s_kk = kk - (int)excl; }
    __syncthreads();
    prefix = s_sel;
    kk = s_kk;
    __syncthreads();
  }
  float med = __uint_as_float(prefix);

  // combined
  for (int i = tid; i < TT; i += 256) {
    float cv = expf(-fabsf(s_dist[i] - med) / 0.1f) * s_aw[i];
    s_comb[i] = cv;
    comb_out[b * TT + i] = cv;
  }
  __syncthreads();

  // greedy K-selection (first-occurrence argmax semantics)
  int picks[KK];
  for (int k = 0; k < KK; ++k) {
    float best = -INFINITY; int bi = 1 << 30;
    for (int i = tid; i < TT; i += 256) {
      float cv = s_comb[i];
      float sc = (k == 0) ? cv : ((cv < 0.0f) ? -INFINITY : s_mind[i] * cv);
      if (sc > best) { best = sc; bi = i; }
    }
#pragma unroll
    for (int off = 32; off; off >>= 1) {
      float ov = __shfl_xor(best, off, 64);
      int oi = __shfl_xor(bi, off, 64);
      if (ov > best || (ov == best && oi < bi)) { best = ov; bi = oi; }
    }
    if (lane == 0) { wv[wave] = best; wi[wave] = bi; }
    __syncthreads();
    if (tid == 0) {
      float bb2 = wv[0]; int ii = wi[0];
#pragma unroll
      for (int w = 1; w < 4; ++w)
        if (wv[w] > bb2 || (wv[w] == bb2 && wi[w] < ii)) { bb2 = wv[w]; ii = wi[w]; }
      s_pick = ii;
      s_comb[ii] = -1.0f;
    }
    __syncthreads();
    int pick = s_pick;
    picks[k] = pick;
    for (int i = tid; i < TT; i += 256) {
      float dnew = fabsf((float)(i - pick));
      s_mind[i] = (k == 0) ? dnew : fminf(s_mind[i], dnew);
    }
    // no barrier: s_mind[i] self-owned; s_comb[pick] synced above
  }
  if (tid < KK) idx_out[b * KK + tid] = (float)picks[tid];

  // gather rep (reuse s_aw+s_comb area is not safe typed-wise; use own buffer via s_dist? keep separate)
  __shared__ float repb[KK * DD];
  float4* repb4 = (float4*)repb;
  float4* rep4 = (float4*)(rep + (size_t)b * KK * DD);
  for (int e = tid; e < KK * (DD / 4); e += 256) {
    int k = e >> 8, d4 = e & 255;
    const float4* vrow = (const float4*)(video + ((size_t)(b * TT + picks[0])) * DD);
    // picks[k] is uniform across threads (from s_pick broadcast) — index directly
    vrow = (const float4*)(video + ((size_t)(b * TT + picks[e >> 8])) * DD);
    float4 v = vrow[d4];
    rep4[(size_t)k * (DD / 4) + d4] = v;
    repb4[k * (DD / 4) + d4] = v;
  }
  __syncthreads();
  // diversity partial
  const int pk[15] = {0,0,0,0,0,1,1,1,1,2,2,2,3,3,4};
  const int pj[15] = {1,2,3,4,5,2,3,4,5,3,4,5,4,5,5};
  float divacc = 0.0f;
  for (int pid = wave; pid < 15; pid += 4) {
    int a = pk[pid], j = pj[pid];
    float part = 0.0f;
    for (int d = lane; d < DD; d += 64) part += repb[a * DD + d] * repb[j * DD + d];
#pragma unroll
    for (int off = 32; off; off >>= 1) part += __shfl_xor(part, off, 64);
    if (lane == 0) divacc += part * part;
  }
  if (lane == 0) wdiv[wave] = divacc;
  __syncthreads();
  if (tid == 0) {
    float div = wdiv[0] + wdiv[1] + wdiv[2] + wdiv[3];
    float rd[KK], srt[KK];
#pragma unroll
    for (int k = 0; k < KK; ++k) { rd[k] = s_dist[picks[k]]; srt[k] = rd[k]; }
    for (int a = 1; a < KK; ++a) {
      float key = srt[a]; int b2 = a - 1;
      while (b2 >= 0 && srt[b2] > key) { srt[b2 + 1] = srt[b2]; --b2; }
      srt[b2 + 1] = key;
    }
    float target = srt[(KK - 1) / 2];
    float ell = 0.0f, cons = 0.0f;
#pragma unroll
    for (int k = 0; k < KK; ++k) { float d = rd[k] - target; ell += d * d; cons += rd[k]; }
    float partial = ell * (1.0f / 48.0f) + 0.1f * cons * (1.0f / 48.0f) + 0.05f * div * (1.0f / 288.0f);
    atomicAdd(loss_out, partial);
  }
}

extern "C" void kernel_launch(void* const* d_in, const int* in_sizes, int n_in,
                              void* d_out, int out_size, void* d_ws, size_t ws_size,
                              hipStream_t stream) {
  const float* video = (const float*)d_in[0];
  const float* qe    = (const float*)d_in[1];
  const float* mu_w1 = (const float*)d_in[2];
  const float* mu_b1 = (const float*)d_in[3];
  const float* mu_g  = (const float*)d_in[4];
  const float* mu_be = (const float*)d_in[5];
  const float* mu_w2 = (const float*)d_in[6];
  const float* mu_b2 = (const float*)d_in[7];
  const float* sg_w1 = (const float*)d_in[8];
  const float* sg_b1 = (const float*)d_in[9];
  const float* sg_g  = (const float*)d_in[10];
  const float* sg_be = (const float*)d_in[11];
  const float* sg_w2 = (const float*)d_in[12];
  const float* sg_b2 = (const float*)d_in[13];
  const float* in_w  = (const float*)d_in[14];
  const float* in_b  = (const float*)d_in[15];
  float* out = (float*)d_out;
  float* ws  = (float*)d_ws;

  k_gemv_pre<<<512, 256, 0, stream>>>(qe, mu_w1, sg_w1, mu_b1, sg_b1, ws + WS_X1);
  k_ln<<<16, 256, 0, stream>>>(ws + WS_X1, mu_g, mu_be, sg_g, sg_be, ws + WS_H);
  k_gemv_mid<<<512, 256, 0, stream>>>(ws + WS_H, mu_w2, sg_w2, mu_b2, sg_b2,
                                      out + OFF_MU, out + OFF_SG, ws + WS_ISIG);
  k_gemv_q<<<256, 256, 0, stream>>>(out + OFF_MU, in_w, in_b, ws + WS_Q);
  k_p<<<32, 256, 0, stream>>>(ws + WS_Q, in_w, in_b, ws + WS_P, ws + WS_C);
  k_main<<<2048, 256, 0, stream>>>(video, out + OFF_MU, ws + WS_ISIG, ws + WS_P, ws + WS_C,
                                   out + OFF_DIST, ws + WS_SCORES, out + OFF_LOSS);
  k_epilogue<<<8, 256, 0, stream>>>(ws + WS_SCORES, out + OFF_DIST, video,
                                    out + OFF_COMB, out + OFF_IDX, out + OFF_REP, out + OFF_LOSS);
}

// Round 4
// 332.945 us; speedup vs baseline: 1.7019x; 1.1434x over previous
//
#include <hip/hip_runtime.h>
#include <math.h>

// ---------------- problem constants ----------------
#define BD   8       // batch
#define TT   4096    // time
#define DD   1024    // feature dim
#define HH   8       // heads
#define KK   6       // picks
// d_out layout (floats): rep | indices | combined | dist | mu_q | sigma_q | loss
#define OFF_REP   0
#define OFF_IDX   49152
#define OFF_COMB  49200
#define OFF_DIST  81968
#define OFF_MU    114736
#define OFF_SG    122928
#define OFF_LOSS  131120
// ws layout (floats)
#define WS_X1     0        // 2*8*1024
#define WS_H      16384    // 2*8*1024
#define WS_Q      32768    // 8*1024
#define WS_P      40960    // 8*8*1024
#define WS_C      106496   // 64
#define WS_ISIG   106560   // 8*1024
#define WS_SCORES 114752   // 8*8*4096

#define INV_SQRT_DH 0.08838834764831845f  // 1/sqrt(128)

__device__ __forceinline__ float softplus_f(float x) {
  return fmaxf(x, 0.0f) + log1pf(expf(-fabsf(x)));
}

// ---- shared GEMV core: out[b,row] = in[b,:] . W[row,:]  (8 batches, wave per row)
__device__ __forceinline__ void gemv_rows_core(const float* __restrict__ in,
                                               const float* __restrict__ W,
                                               int row, float (*s_in)[DD], float acc[8]) {
  int tid = threadIdx.x;
  const float4* in4 = (const float4*)in;
  float4* s4 = (float4*)&s_in[0][0];
  for (int i = tid; i < 2048; i += 256) s4[i] = in4[i];
  __syncthreads();
  int lane = tid & 63;
  const float4* wr4 = (const float4*)(W + (size_t)row * DD);
#pragma unroll
  for (int b = 0; b < 8; ++b) acc[b] = 0.0f;
#pragma unroll
  for (int i = 0; i < 4; ++i) {
    int d4 = i * 64 + lane;
    float4 w4 = wr4[d4];
#pragma unroll
    for (int b = 0; b < 8; ++b) {
      float4 q4 = ((const float4*)&s_in[b][0])[d4];
      acc[b] += w4.x * q4.x + w4.y * q4.y + w4.z * q4.z + w4.w * q4.w;
    }
  }
#pragma unroll
  for (int off = 32; off; off >>= 1)
#pragma unroll
    for (int b = 0; b < 8; ++b) acc[b] += __shfl_xor(acc[b], off, 64);
}

// x1[path][b][row] = qe[b]·W{path}[row] + bias
__global__ __launch_bounds__(256) void k_gemv_pre(const float* __restrict__ qe,
    const float* __restrict__ W0, const float* __restrict__ W1,
    const float* __restrict__ b0, const float* __restrict__ b1, float* __restrict__ x1) {
  __shared__ float s_in[8][DD];
  int path = blockIdx.x >> 8;
  int row = (blockIdx.x & 255) * 4 + (threadIdx.x >> 6);
  const float* W = path ? W1 : W0;
  const float* bb = path ? b1 : b0;
  float acc[8];
  gemv_rows_core(qe, W, row, s_in, acc);
  if ((threadIdx.x & 63) == 0) {
    float bv = bb[row];
#pragma unroll
    for (int b = 0; b < 8; ++b) x1[path * 8192 + b * DD + row] = acc[b] + bv;
  }
}

// LN + relu per (path,b) row of 1024
__global__ __launch_bounds__(256) void k_ln(const float* __restrict__ x1,
    const float* __restrict__ g0, const float* __restrict__ be0,
    const float* __restrict__ g1, const float* __restrict__ be1, float* __restrict__ h) {
  int path = blockIdx.x >> 3, b = blockIdx.x & 7;
  const float* x = x1 + path * 8192 + b * DD;
  const float* g = path ? g1 : g0;
  const float* be = path ? be1 : be0;
  __shared__ float sx[DD];
  __shared__ float red[256];
  int tid = threadIdx.x;
  float ps = 0.0f;
  for (int i = tid; i < DD; i += 256) { float v = x[i]; sx[i] = v; ps += v; }
  red[tid] = ps; __syncthreads();
  for (int off = 128; off; off >>= 1) { if (tid < off) red[tid] += red[tid + off]; __syncthreads(); }
  float mean = red[0] * (1.0f / 1024.0f);
  __syncthreads();
  float pv = 0.0f;
  for (int i = tid; i < DD; i += 256) { float d = sx[i] - mean; pv += d * d; }
  red[tid] = pv; __syncthreads();
  for (int off = 128; off; off >>= 1) { if (tid < off) red[tid] += red[tid + off]; __syncthreads(); }
  float var = red[0] * (1.0f / 1024.0f);
  float inv = 1.0f / sqrtf(var + 1e-5f);
  for (int i = tid; i < DD; i += 256) {
    float v = (sx[i] - mean) * inv * g[i] + be[i];
    h[path * 8192 + b * DD + i] = v > 0.0f ? v : 0.0f;
  }
}

// path0: mu_q; path1: sigma_q = softplus+1e-6, isig = 1/sigma
__global__ __launch_bounds__(256) void k_gemv_mid(const float* __restrict__ h,
    const float* __restrict__ W0, const float* __restrict__ W1,
    const float* __restrict__ b0, const float* __restrict__ b1,
    float* __restrict__ mu_out, float* __restrict__ sg_out, float* __restrict__ isig) {
  __shared__ float s_in[8][DD];
  int path = blockIdx.x >> 8;
  int row = (blockIdx.x & 255) * 4 + (threadIdx.x >> 6);
  const float* W = path ? W1 : W0;
  const float* bb = path ? b1 : b0;
  float acc[8];
  gemv_rows_core(h + path * 8192, W, row, s_in, acc);
  if ((threadIdx.x & 63) == 0) {
    float bv = bb[row];
#pragma unroll
    for (int b = 0; b < 8; ++b) {
      float v = acc[b] + bv;
      if (path == 0) {
        mu_out[b * DD + row] = v;
      } else {
        float sp = softplus_f(v) + 1e-6f;
        sg_out[b * DD + row] = sp;
        isig[b * DD + row] = 1.0f / sp;
      }
    }
  }
}

// q[b,row] = mu_q[b]·wq[row] + bq[row]   (wq = in_w rows 0..1023)
__global__ __launch_bounds__(256) void k_gemv_q(const float* __restrict__ mu_q,
    const float* __restrict__ in_w, const float* __restrict__ in_b, float* __restrict__ q) {
  __shared__ float s_in[8][DD];
  int row = blockIdx.x * 4 + (threadIdx.x >> 6);
  float acc[8];
  gemv_rows_core(mu_q, in_w, row, s_in, acc);
  if ((threadIdx.x & 63) == 0) {
    float bv = in_b[row];
#pragma unroll
    for (int b = 0; b < 8; ++b) q[b * DD + row] = acc[b] + bv;
  }
}

// p[b,h,j] = (sum_r q[b,h*128+r]*wk[h*128+r,j]) / sqrt(128);  c[b,h] analog with bk
__global__ __launch_bounds__(256) void k_p(const float* __restrict__ q,
    const float* __restrict__ in_w, const float* __restrict__ in_b,
    float* __restrict__ p, float* __restrict__ c) {
  int hh = blockIdx.x >> 2;
  int j0 = (blockIdx.x & 3) * 256;
  __shared__ float qh[8][128];
  for (int i = threadIdx.x; i < 1024; i += 256) {
    int b = i >> 7, r = i & 127;
    qh[b][r] = q[b * DD + hh * 128 + r];
  }
  __syncthreads();
  const float* wbase = in_w + (size_t)(DD + hh * 128) * DD + j0 + threadIdx.x;
  float acc[8];
#pragma unroll
  for (int b = 0; b < 8; ++b) acc[b] = 0.0f;
  for (int r = 0; r < 128; ++r) {
    float w = wbase[(size_t)r * DD];
#pragma unroll
    for (int b = 0; b < 8; ++b) acc[b] += qh[b][r] * w;
  }
#pragma unroll
  for (int b = 0; b < 8; ++b) p[(b * HH + hh) * DD + j0 + threadIdx.x] = acc[b] * INV_SQRT_DH;
  if ((blockIdx.x & 3) == 0 && threadIdx.x < 8) {
    int b = threadIdx.x;
    float cc = 0.0f;
    for (int r = 0; r < 128; ++r) cc += qh[b][r] * in_b[DD + hh * 128 + r];
    c[b * HH + hh] = cc * INV_SQRT_DH;
  }
}

// Big streaming pass: dist[b,t] (f64 acc) and scores[b,h,t]
// Live VGPRs kept ~80 < 128 cap (launch_bounds 256,4) -> no scratch spill.
__global__ __launch_bounds__(256, 4) void k_main(const float* __restrict__ video,
    const float* __restrict__ mu_q, const float* __restrict__ isig,
    const float* __restrict__ p, const float* __restrict__ c,
    float* __restrict__ dist_out, float* __restrict__ scores, float* __restrict__ loss_out) {
  __shared__ float s_mu[DD];
  __shared__ float s_is[DD];
  __shared__ float s_p[HH][DD];
  int b = blockIdx.x >> 8;
  int chunk = blockIdx.x & 255;
  int tid = threadIdx.x;
  int wave = tid >> 6, lane = tid & 63;
  if (blockIdx.x == 0 && tid == 0) loss_out[0] = 0.0f;  // k_epilogue (stream-ordered after) accumulates
  float4* s_mu4 = (float4*)s_mu;
  float4* s_is4 = (float4*)s_is;
  float4* s_p4 = (float4*)&s_p[0][0];
  s_mu4[tid] = ((const float4*)(mu_q + b * DD))[tid];
  s_is4[tid] = ((const float4*)(isig + b * DD))[tid];
  const float4* pg4 = (const float4*)(p + b * HH * DD);
  for (int i = tid; i < 2048; i += 256) s_p4[i] = pg4[i];
  __syncthreads();

  int t0 = chunk * 16 + wave * 4;
  const float4* v4 = (const float4*)(video + ((size_t)(b * TT + t0)) * DD);
  double dacc[4] = {0.0, 0.0, 0.0, 0.0};
  float sacc[4][8];
#pragma unroll
  for (int t = 0; t < 4; ++t)
#pragma unroll
    for (int hh = 0; hh < 8; ++hh) sacc[t][hh] = 0.0f;

#pragma unroll 2
  for (int i = 0; i < 4; ++i) {
    int d4 = i * 64 + lane;
    float4 vv0 = v4[0 * 256 + d4];
    float4 vv1 = v4[1 * 256 + d4];
    float4 vv2 = v4[2 * 256 + d4];
    float4 vv3 = v4[3 * 256 + d4];
    {
      float4 mu4 = s_mu4[d4];
      float4 is4 = s_is4[d4];
      float dx, dy, dz, dw, e;
      dx = vv0.x - mu4.x; dy = vv0.y - mu4.y; dz = vv0.z - mu4.z; dw = vv0.w - mu4.w;
      e = dx * dx * is4.x + dy * dy * is4.y + dz * dz * is4.z + dw * dw * is4.w;
      dacc[0] += (double)e;
      dx = vv1.x - mu4.x; dy = vv1.y - mu4.y; dz = vv1.z - mu4.z; dw = vv1.w - mu4.w;
      e = dx * dx * is4.x + dy * dy * is4.y + dz * dz * is4.z + dw * dw * is4.w;
      dacc[1] += (double)e;
      dx = vv2.x - mu4.x; dy = vv2.y - mu4.y; dz = vv2.z - mu4.z; dw = vv2.w - mu4.w;
      e = dx * dx * is4.x + dy * dy * is4.y + dz * dz * is4.z + dw * dw * is4.w;
      dacc[2] += (double)e;
      dx = vv3.x - mu4.x; dy = vv3.y - mu4.y; dz = vv3.z - mu4.z; dw = vv3.w - mu4.w;
      e = dx * dx * is4.x + dy * dy * is4.y + dz * dz * is4.z + dw * dw * is4.w;
      dacc[3] += (double)e;
    }
#pragma unroll
    for (int hh = 0; hh < 8; ++hh) {
      float4 pp = ((const float4*)&s_p[hh][0])[d4];
      sacc[0][hh] += pp.x * vv0.x + pp.y * vv0.y + pp.z * vv0.z + pp.w * vv0.w;
      sacc[1][hh] += pp.x * vv1.x + pp.y * vv1.y + pp.z * vv1.z + pp.w * vv1.w;
      sacc[2][hh] += pp.x * vv2.x + pp.y * vv2.y + pp.z * vv2.z + pp.w * vv2.w;
      sacc[3][hh] += pp.x * vv3.x + pp.y * vv3.y + pp.z * vv3.z + pp.w * vv3.w;
    }
  }
#pragma unroll
  for (int off = 32; off; off >>= 1) {
#pragma unroll
    for (int t = 0; t < 4; ++t) {
      dacc[t] += __shfl_xor(dacc[t], off, 64);
#pragma unroll
      for (int hh = 0; hh < 8; ++hh) sacc[t][hh] += __shfl_xor(sacc[t][hh], off, 64);
    }
  }
  if (lane < 4) {
    int t = lane;
    int tt = t0 + t;
    dist_out[b * TT + tt] = (float)dacc[t];
#pragma unroll
    for (int hh = 0; hh < 8; ++hh)
      scores[(size_t)(b * HH + hh) * TT + tt] = sacc[t][hh] + c[b * HH + hh];
  }
}

// Fused epilogue, one 1024-thread block per b (16 waves/CU for latency hiding):
//   softmax stats -> attn mean -> radix-select median -> combined (regs) ->
//   greedy-K (all-register) -> gather rep -> loss partial (atomicAdd).
__global__ __launch_bounds__(1024) void k_epilogue(const float* __restrict__ scores,
    const float* __restrict__ dist, const float* __restrict__ video,
    float* __restrict__ comb_out, float* __restrict__ idx_out,
    float* __restrict__ rep, float* __restrict__ loss_out) {
  int b = blockIdx.x;
  int tid = threadIdx.x;
  int wave = tid >> 6, lane = tid & 63;
  __shared__ float s_dist[TT];
  __shared__ float s_hm[HH], s_hs[HH];
  __shared__ float s_w16[16], s_w16b[16];
  __shared__ unsigned hist[256];
  __shared__ unsigned wsum[4];
  __shared__ unsigned s_sel;
  __shared__ int s_kk;
  __shared__ float wv[16];
  __shared__ int wi[16];
  __shared__ int s_pick;
  __shared__ float wdiv[16];
  __shared__ float repb[KK * DD];

  // ---- pass 1: per-head max & inv-sum (128 threads = 2 waves per head) ----
  {
    int h = tid >> 7, lt = tid & 127;
    const float4* srow4 = (const float4*)(scores + ((size_t)(b * HH + h)) * TT);
    float m = -INFINITY;
#pragma unroll
    for (int i = 0; i < 8; ++i) {
      float4 v = srow4[lt + i * 128];
      m = fmaxf(m, fmaxf(fmaxf(v.x, v.y), fmaxf(v.z, v.w)));
    }
#pragma unroll
    for (int off = 32; off; off >>= 1) m = fmaxf(m, __shfl_xor(m, off, 64));
    if (lane == 0) s_w16[wave] = m;
    __syncthreads();
    float mh = fmaxf(s_w16[h * 2], s_w16[h * 2 + 1]);
    float s = 0.0f;
#pragma unroll
    for (int i = 0; i < 8; ++i) {
      float4 v = srow4[lt + i * 128];
      s += expf(v.x - mh) + expf(v.y - mh) + expf(v.z - mh) + expf(v.w - mh);
    }
#pragma unroll
    for (int off = 32; off; off >>= 1) s += __shfl_xor(s, off, 64);
    if (lane == 0) s_w16b[wave] = s;
    __syncthreads();
    if (lt == 0) { s_hm[h] = mh; s_hs[h] = 1.0f / (s_w16b[h * 2] + s_w16b[h * 2 + 1]); }
    __syncthreads();
  }

  // ---- pass 2: attn mean + stage dist (one float4 per thread) ----
  float4 d4 = ((const float4*)(dist + b * TT))[tid];
  ((float4*)s_dist)[tid] = d4;
  float4 aw = make_float4(0.f, 0.f, 0.f, 0.f);
#pragma unroll
  for (int h = 0; h < HH; ++h) {
    float4 sc = ((const float4*)(scores + ((size_t)(b * HH + h)) * TT))[tid];
    float mh = s_hm[h], is = s_hs[h];
    aw.x += expf(sc.x - mh) * is;
    aw.y += expf(sc.y - mh) * is;
    aw.z += expf(sc.z - mh) * is;
    aw.w += expf(sc.w - mh) * is;
  }
  aw.x *= 0.125f; aw.y *= 0.125f; aw.z *= 0.125f; aw.w *= 0.125f;
  uint4 keys;
  keys.x = __float_as_uint(d4.x);
  keys.y = __float_as_uint(d4.y);
  keys.z = __float_as_uint(d4.z);
  keys.w = __float_as_uint(d4.w);
  __syncthreads();

  // ---- radix-select median: rank 2047 (positive floats ~ uint order) ----
  unsigned prefix = 0;
  int kk = (TT - 1) / 2;
  for (int pass = 0; pass < 4; ++pass) {
    int shift = 24 - 8 * pass;
    if (tid < 256) hist[tid] = 0;
    __syncthreads();
    {
      unsigned karr[4] = {keys.x, keys.y, keys.z, keys.w};
#pragma unroll
      for (int j = 0; j < 4; ++j) {
        unsigned key = karr[j];
        bool ok = (pass == 0) || ((key >> (shift + 8)) == prefix);
        if (ok) atomicAdd(&hist[(key >> shift) & 255], 1u);
      }
    }
    __syncthreads();
    unsigned hcnt = 0, inc = 0;
    if (tid < 256) {
      hcnt = hist[tid];
      inc = hcnt;
#pragma unroll
      for (int off = 1; off < 64; off <<= 1) {
        unsigned v = __shfl_up(inc, off, 64);
        if (lane >= off) inc += v;
      }
      if (lane == 63) wsum[wave] = inc;
    }
    __syncthreads();
    if (tid < 256) {
      unsigned base = 0;
      for (int w = 0; w < wave; ++w) base += wsum[w];
      unsigned excl = base + inc - hcnt;
      if ((int)excl <= kk && kk < (int)(excl + hcnt)) {
        s_sel = (prefix << 8) | (unsigned)tid;
        s_kk = kk - (int)excl;
      }
    }
    __syncthreads();
    prefix = s_sel;
    kk = s_kk;
    __syncthreads();
  }
  float med = __uint_as_float(prefix);

  // ---- combined (registers) + global write ----
  float4 cb;
  cb.x = expf(-fabsf(d4.x - med) / 0.1f) * aw.x;
  cb.y = expf(-fabsf(d4.y - med) / 0.1f) * aw.y;
  cb.z = expf(-fabsf(d4.z - med) / 0.1f) * aw.z;
  cb.w = expf(-fabsf(d4.w - med) / 0.1f) * aw.w;
  ((float4*)(comb_out + b * TT))[tid] = cb;

  // ---- greedy K-selection, all-register (first-occurrence argmax) ----
  float4 md = make_float4(0.f, 0.f, 0.f, 0.f);
  int i0 = tid * 4;
  int picks[KK];
  for (int k = 0; k < KK; ++k) {
    float carr[4] = {cb.x, cb.y, cb.z, cb.w};
    float marr[4] = {md.x, md.y, md.z, md.w};
    float best = -INFINITY; int bi = 1 << 30;
#pragma unroll
    for (int j = 0; j < 4; ++j) {
      float cv = carr[j];
      float sc = (k == 0) ? cv : ((cv < 0.0f) ? -INFINITY : marr[j] * cv);
      if (sc > best) { best = sc; bi = i0 + j; }
    }
#pragma unroll
    for (int off = 32; off; off >>= 1) {
      float ov = __shfl_xor(best, off, 64);
      int oi = __shfl_xor(bi, off, 64);
      if (ov > best || (ov == best && oi < bi)) { best = ov; bi = oi; }
    }
    if (lane == 0) { wv[wave] = best; wi[wave] = bi; }
    __syncthreads();
    if (tid == 0) {
      float bb2 = wv[0]; int ii = wi[0];
#pragma unroll
      for (int w = 1; w < 16; ++w)
        if (wv[w] > bb2 || (wv[w] == bb2 && wi[w] < ii)) { bb2 = wv[w]; ii = wi[w]; }
      s_pick = ii;
    }
    __syncthreads();
    int pick = s_pick;
    picks[k] = pick;
    // mask in registers (owning thread only) + update min-dist in registers
    if ((pick >> 2) == tid) {
      int j = pick & 3;
      if (j == 0) cb.x = -1.0f; else if (j == 1) cb.y = -1.0f;
      else if (j == 2) cb.z = -1.0f; else cb.w = -1.0f;
    }
    float dn0 = fabsf((float)(i0 + 0 - pick));
    float dn1 = fabsf((float)(i0 + 1 - pick));
    float dn2 = fabsf((float)(i0 + 2 - pick));
    float dn3 = fabsf((float)(i0 + 3 - pick));
    if (k == 0) { md.x = dn0; md.y = dn1; md.z = dn2; md.w = dn3; }
    else { md.x = fminf(md.x, dn0); md.y = fminf(md.y, dn1);
           md.z = fminf(md.z, dn2); md.w = fminf(md.w, dn3); }
  }
  if (tid < KK) idx_out[b * KK + tid] = (float)picks[tid];

  // ---- gather rep ----
  float4* repb4 = (float4*)repb;
  float4* rep4 = (float4*)(rep + (size_t)b * KK * DD);
  for (int e = tid; e < KK * (DD / 4); e += 1024) {
    int k = e >> 8, dd4 = e & 255;
    const float4* vrow = (const float4*)(video + ((size_t)(b * TT + picks[k])) * DD);
    float4 v = vrow[dd4];
    rep4[(size_t)k * (DD / 4) + dd4] = v;
    repb4[e] = v;
  }
  __syncthreads();

  // ---- diversity: 15 pairs over 16 waves ----
  const int pk[15] = {0,0,0,0,0,1,1,1,1,2,2,2,3,3,4};
  const int pj[15] = {1,2,3,4,5,2,3,4,5,3,4,5,4,5,5};
  float divacc = 0.0f;
  if (wave < 15) {
    int a = pk[wave], j = pj[wave];
    float part = 0.0f;
    for (int d = lane; d < DD; d += 64) part += repb[a * DD + d] * repb[j * DD + d];
#pragma unroll
    for (int off = 32; off; off >>= 1) part += __shfl_xor(part, off, 64);
    if (lane == 0) divacc = part * part;
  }
  if (lane == 0) wdiv[wave] = (wave < 15) ? divacc : 0.0f;
  __syncthreads();

  if (tid == 0) {
    float div = 0.0f;
#pragma unroll
    for (int w = 0; w < 15; ++w) div += wdiv[w];
    float rd[KK], srt[KK];
#pragma unroll
    for (int k = 0; k < KK; ++k) { rd[k] = s_dist[picks[k]]; srt[k] = rd[k]; }
    for (int a = 1; a < KK; ++a) {
      float key = srt[a]; int b2 = a - 1;
      while (b2 >= 0 && srt[b2] > key) { srt[b2 + 1] = srt[b2]; --b2; }
      srt[b2 + 1] = key;
    }
    float target = srt[(KK - 1) / 2];
    float ell = 0.0f, cons = 0.0f;
#pragma unroll
    for (int k = 0; k < KK; ++k) { float d = rd[k] - target; ell += d * d; cons += rd[k]; }
    float partial = ell * (1.0f / 48.0f) + 0.1f * cons * (1.0f / 48.0f) + 0.05f * div * (1.0f / 288.0f);
    atomicAdd(loss_out, partial);
  }
}

extern "C" void kernel_launch(void* const* d_in, const int* in_sizes, int n_in,
                              void* d_out, int out_size, void* d_ws, size_t ws_size,
                              hipStream_t stream) {
  const float* video = (const float*)d_in[0];
  const float* qe    = (const float*)d_in[1];
  const float* mu_w1 = (const float*)d_in[2];
  const float* mu_b1 = (const float*)d_in[3];
  const float* mu_g  = (const float*)d_in[4];
  const float* mu_be = (const float*)d_in[5];
  const float* mu_w2 = (const float*)d_in[6];
  const float* mu_b2 = (const float*)d_in[7];
  const float* sg_w1 = (const float*)d_in[8];
  const float* sg_b1 = (const float*)d_in[9];
  const float* sg_g  = (const float*)d_in[10];
  const float* sg_be = (const float*)d_in[11];
  const float* sg_w2 = (const float*)d_in[12];
  const float* sg_b2 = (const float*)d_in[13];
  const float* in_w  = (const float*)d_in[14];
  const float* in_b  = (const float*)d_in[15];
  float* out = (float*)d_out;
  float* ws  = (float*)d_ws;

  k_gemv_pre<<<512, 256, 0, stream>>>(qe, mu_w1, sg_w1, mu_b1, sg_b1, ws + WS_X1);
  k_ln<<<16, 256, 0, stream>>>(ws + WS_X1, mu_g, mu_be, sg_g, sg_be, ws + WS_H);
  k_gemv_mid<<<512, 256, 0, stream>>>(ws + WS_H, mu_w2, sg_w2, mu_b2, sg_b2,
                                      out + OFF_MU, out + OFF_SG, ws + WS_ISIG);
  k_gemv_q<<<256, 256, 0, stream>>>(out + OFF_MU, in_w, in_b, ws + WS_Q);
  k_p<<<32, 256, 0, stream>>>(ws + WS_Q, in_w, in_b, ws + WS_P, ws + WS_C);
  k_main<<<2048, 256, 0, stream>>>(video, out + OFF_MU, ws + WS_ISIG, ws + WS_P, ws + WS_C,
                                   out + OFF_DIST, ws + WS_SCORES, out + OFF_LOSS);
  k_epilogue<<<8, 1024, 0, stream>>>(ws + WS_SCORES, out + OFF_DIST, video,
                                     out + OFF_COMB, out + OFF_IDX, out + OFF_REP, out + OFF_LOSS);
}